// Round 3
// baseline (447.022 us; speedup 1.0000x reference)
//
#include <hip/hip_runtime.h>

// Problem constants (fixed by the reference's setup_inputs)
#define NN   100000      // nodes
#define EE   1600000     // num_edge
#define EROW 4800000     // edge_index row length (3*NUM_EDGE)

typedef _Float16 half8 __attribute__((ext_vector_type(8)));
typedef _Float16 half4 __attribute__((ext_vector_type(4)));
typedef float    f32x4 __attribute__((ext_vector_type(4)));

__device__ __forceinline__ float4 ld4(const float* p){ return *(const float4*)p; }

// Split fp32 -> (hi fp16) + (lo fp16, scaled by 2048). Packed lo16=hi, hi16=lo.
__device__ __forceinline__ unsigned splitf(float v) {
    _Float16 h = (_Float16)v;
    float r = v - (float)h;
    _Float16 l = (_Float16)(r * 2048.0f);
    union { _Float16 f; unsigned short u; } uh, ul;
    uh.f = h; ul.f = l;
    return (unsigned)uh.u | ((unsigned)ul.u << 16);
}

// ---------------------------------------------------------------------------
// Weight prep: split W_lin (256x256), W_lin2 (128x256), repacked W_fc1
// (128x128: row j = W_fc1[j&63][(j>>6)*128 ..]) into interleaved half2 planes.
// ---------------------------------------------------------------------------
__global__ __launch_bounds__(256)
void prep_w(const float* __restrict__ W1, const float* __restrict__ W2,
            const float* __restrict__ W3, unsigned* __restrict__ o1,
            unsigned* __restrict__ o2, unsigned* __restrict__ o3)
{
    int idx = blockIdx.x * 256 + threadIdx.x;   // 448 blocks = 114688 threads
    if (idx < 65536) {
        o1[idx] = splitf(W1[idx]);
    } else if (idx < 98304) {
        int i = idx - 65536;
        o2[i] = splitf(W2[i]);
    } else {
        int i = idx - 98304;
        int j = i >> 7, k = i & 127;
        o3[i] = splitf(W3[(j & 63) * 256 + (j >> 6) * 128 + k]);
    }
}

// ---------------------------------------------------------------------------
// MFMA split-fp16 GEMM: C[M x No] = A[M x K] @ B[No x K]^T (+epilogue).
// 256 thr = 4 waves, wave grid 2x2, wave tile 64x64 (4x4 of 16x16x32 f16).
// 3 MFMA passes: acc_hi += Ah*Bh; acc_mid += Ah*Bl + Al*Bh; C = hi + mid/2048.
// LDS double-buffered (80 KB total), ONE barrier per K-tile.
//
// R3 change: A (the HBM stream) is prefetched DEPTH-2 via two ping-pong
// staged-register sets — loads for tile kt+2 issue at iter kt, so A bytes
// stay in flight continuously instead of burst-and-drain once per iter
// (Little's-law starvation was capping HBM at ~2 TB/s). B (L2-resident
// weights) stays depth-1. Funded by streaming B-fragments per-j inside the
// MFMA loop (cuts B-frag liveness 32->8 dwords). s_setprio(1) around the
// MFMA cluster arbitrates between the two independently-phased blocks/CU.
//
// SRCA 0: A = trace fp32 (gathered 2-plane, split on the fly). 1: split plane.
// EPI  0: relu, store split plane. 1: row-L2-normalize, store split plane.
//      2: += b_fc1 on cols 0-63, store fp32 + fp16 copies.
// ---------------------------------------------------------------------------
template<int SRCA, int EPI>
__global__ __launch_bounds__(256, 2)
void gemm_mfma(const void* __restrict__ Asrc, const unsigned* __restrict__ Bw,
               const float* __restrict__ bias, unsigned* __restrict__ outS,
               float* __restrict__ outF, unsigned short* __restrict__ outH,
               int M, int K, int No)
{
    // 40-halfword rows: 80 B stride (16B-aligned), 2-way (free) bank tiling.
    __shared__ __align__(16) _Float16 Ah[2][128][40];
    __shared__ __align__(16) _Float16 Al[2][128][40];
    __shared__ __align__(16) _Float16 Bh[2][128][40];
    __shared__ __align__(16) _Float16 Bl[2][128][40];
    // EPI==1 cross-wave row-ssq scratch aliases Ah after the K-loop.
    float* sqv = (float*)&Ah[0][0][0];   // viewed as [128][2]

    const int t     = threadIdx.x;
    const int wm    = (t >> 6) >> 1;   // wave m index (0..1)
    const int wn    = (t >> 6) & 1;    // wave n index (0..1)
    const int lane  = t & 63;
    const int lm    = lane & 15;
    const int q     = lane >> 4;
    const int mBase = blockIdx.x * 128;
    const int nBase = blockIdx.y * 128;

    const int srow = t >> 3;           // staging row 0..31 (+32*it)
    const int sseg = (t & 7) * 4;      // staging k-offset (elems)

    f32x4 aH[4][4], aM[4][4];
#pragma unroll
    for (int i = 0; i < 4; ++i)
#pragma unroll
        for (int j = 0; j < 4; ++j) {
            aH[i][j] = (f32x4){0.f, 0.f, 0.f, 0.f};
            aM[i][j] = (f32x4){0.f, 0.f, 0.f, 0.f};
        }

    // Two staged A sets (ping-pong, depth-2 prefetch) + one B set (depth-1).
    uint2 sAh[2][4], sAl[2][4], sBh[4], sBl[4];

    auto loadA = [&](int set, int k0) {
#pragma unroll
        for (int it = 0; it < 4; ++it) {
            const int row = srow + it * 32;
            int rg = mBase + row; rg = rg < M ? rg : M - 1;
            if (SRCA == 0) {
                const int k = k0 + sseg;    // whole 32-chunk inside one L-plane
                const float* ap = (const float*)Asrc
                    + (size_t)(k >> 7) * ((size_t)NN * 128)
                    + (size_t)rg * 128 + (k & 127);
                float4 f = ld4(ap);
                unsigned p0 = splitf(f.x), p1 = splitf(f.y);
                unsigned p2 = splitf(f.z), p3 = splitf(f.w);
                sAh[set][it].x = (p0 & 0xffffu) | (p1 << 16);
                sAh[set][it].y = (p2 & 0xffffu) | (p3 << 16);
                sAl[set][it].x = (p0 >> 16) | (p1 & 0xffff0000u);
                sAl[set][it].y = (p2 >> 16) | (p3 & 0xffff0000u);
            } else {
                const unsigned* ap = (const unsigned*)Asrc + (size_t)rg * K + k0 + sseg;
                uint4 u = *(const uint4*)ap;
                sAh[set][it].x = (u.x & 0xffffu) | (u.y << 16);
                sAh[set][it].y = (u.z & 0xffffu) | (u.w << 16);
                sAl[set][it].x = (u.x >> 16) | (u.y & 0xffff0000u);
                sAl[set][it].y = (u.z >> 16) | (u.w & 0xffff0000u);
            }
        }
    };

    auto loadB = [&](int k0) {
#pragma unroll
        for (int it = 0; it < 4; ++it) {
            const int row = srow + it * 32;
            const unsigned* bp = Bw + (size_t)(nBase + row) * K + k0 + sseg;
            uint4 ub = *(const uint4*)bp;
            sBh[it].x = (ub.x & 0xffffu) | (ub.y << 16);
            sBh[it].y = (ub.z & 0xffffu) | (ub.w << 16);
            sBl[it].x = (ub.x >> 16) | (ub.y & 0xffff0000u);
            sBl[it].y = (ub.z >> 16) | (ub.w & 0xffff0000u);
        }
    };

    const int nk = K / 32;
    loadA(0, 0);
    loadB(0);
    if (nk > 1) loadA(1, 32);          // depth-2: tile kt+1 already in flight

    for (int kt = 0; kt < nk; ++kt) {
        const int b = kt & 1;
        const int s = kt & 1;          // A staged set holding tile kt
        // Write staged regs -> LDS[b]. Safe without a leading barrier: any
        // wave still reading buffer b is at iteration kt-2, separated from
        // this write by the kt-1 barrier it must pass after its reads.
#pragma unroll
        for (int it = 0; it < 4; ++it) {
            const int row = srow + it * 32;
            *(uint2*)&Ah[b][row][sseg] = sAh[s][it];
            *(uint2*)&Al[b][row][sseg] = sAl[s][it];
            *(uint2*)&Bh[b][row][sseg] = sBh[it];
            *(uint2*)&Bl[b][row][sseg] = sBl[it];
        }
        __syncthreads();
        if (kt + 1 < nk) loadB((kt + 1) * 32);       // B: depth-1 (L2-hot)
        if (kt + 2 < nk) loadA(s, (kt + 2) * 32);    // A: depth-2 (HBM), reuse set

        half8 fAh[4], fAl[4];
#pragma unroll
        for (int i = 0; i < 4; ++i) {
            fAh[i] = *(const half8*)&Ah[b][wm * 64 + i * 16 + lm][q * 8];
            fAl[i] = *(const half8*)&Al[b][wm * 64 + i * 16 + lm][q * 8];
        }
        __builtin_amdgcn_s_setprio(1);
#pragma unroll
        for (int j = 0; j < 4; ++j) {
            half8 fBh = *(const half8*)&Bh[b][wn * 64 + j * 16 + lm][q * 8];
            half8 fBl = *(const half8*)&Bl[b][wn * 64 + j * 16 + lm][q * 8];
#pragma unroll
            for (int i = 0; i < 4; ++i) {
                aH[i][j] = __builtin_amdgcn_mfma_f32_16x16x32_f16(fAh[i], fBh, aH[i][j], 0, 0, 0);
                aM[i][j] = __builtin_amdgcn_mfma_f32_16x16x32_f16(fAh[i], fBl, aM[i][j], 0, 0, 0);
                aM[i][j] = __builtin_amdgcn_mfma_f32_16x16x32_f16(fAl[i], fBh, aM[i][j], 0, 0, 0);
            }
        }
        __builtin_amdgcn_s_setprio(0);
    }

    // Combine split accumulators: C = hi + mid/2048
    const float cM = 1.0f / 2048.0f;
#pragma unroll
    for (int i = 0; i < 4; ++i)
#pragma unroll
        for (int j = 0; j < 4; ++j)
            aH[i][j] = aH[i][j] + aM[i][j] * cM;

    float nm[4][4];
    if (EPI == 1) {
        __syncthreads();   // all frag reads done before aliasing Ah as sqv
#pragma unroll
        for (int i = 0; i < 4; ++i)
#pragma unroll
            for (int r = 0; r < 4; ++r) {
                float s = 0.f;
#pragma unroll
                for (int j = 0; j < 4; ++j) { float x = aH[i][j][r]; s = fmaf(x, x, s); }
#pragma unroll
                for (int off = 1; off < 16; off <<= 1) s += __shfl_xor(s, off, 16);
                if (lm == 0) sqv[(wm * 64 + i * 16 + q * 4 + r) * 2 + wn] = s;
            }
        __syncthreads();
#pragma unroll
        for (int i = 0; i < 4; ++i)
#pragma unroll
            for (int r = 0; r < 4; ++r) {
                const int rl = wm * 64 + i * 16 + q * 4 + r;
                nm[i][r] = fmaxf(sqrtf(sqv[rl * 2] + sqv[rl * 2 + 1]), 1e-12f);
            }
    }

    float bj[4] = {0.f, 0.f, 0.f, 0.f};
    if (EPI == 2 && wn == 0) {
#pragma unroll
        for (int j = 0; j < 4; ++j) bj[j] = bias[j * 16 + lm];
    }

#pragma unroll
    for (int i = 0; i < 4; ++i)
#pragma unroll
        for (int r = 0; r < 4; ++r) {
            const int m = mBase + wm * 64 + i * 16 + q * 4 + r;
            if (m < M) {
#pragma unroll
                for (int j = 0; j < 4; ++j) {
                    const int c = nBase + wn * 64 + j * 16 + lm;
                    float v = aH[i][j][r];
                    if (EPI == 0) { v = fmaxf(v, 0.f); outS[(size_t)m * No + c] = splitf(v); }
                    if (EPI == 1) { v = v / nm[i][r];  outS[(size_t)m * No + c] = splitf(v); }
                    if (EPI == 2) {
                        v += bj[j];
                        outF[(size_t)m * No + c] = v;
                        union { _Float16 f; unsigned short u; } cv; cv.f = (_Float16)v;
                        outH[(size_t)m * No + c] = cv.u;
                    }
                }
            }
        }
}

// ---------------------------------------------------------------------------
// Edge kernel: 128 edges/block, 16 lanes/edge, 8 edges/lane-group.
// Fast path gathers the fp16 p-table (8 B/lane per edge-half). The decision
// only needs the SIGN of the score gap: gap = sum relu(a+c)*(w0-w1) + dB + dg,
// so we accumulate ONE dot with dk = w0-w1 and butterfly-reduce 2 values
// (sc, eb). Certified bound: |fast gap - exact gap| <=
// 2^-10 * sum |dk|*(|a|+|c|) + 2e-5 slack; if |gap| <= bound, re-gather fp32
// and recompute exactly (path unchanged — it is the arbiter). Butterfly
// results are bit-identical across lanes -> branch uniform per 16-lane group.
// ---------------------------------------------------------------------------
#define EPB 128
__global__ __launch_bounds__(256, 4)
void edge_k(const unsigned short* __restrict__ pH, const float* __restrict__ p,
            const int* __restrict__ ei, const float* __restrict__ gum,
            const float* __restrict__ W2, const float* __restrict__ b2,
            float* __restrict__ out)
{
    __shared__ int   sidx[EPB];
    __shared__ int   didx[EPB];
    __shared__ float gl[2 * EPB];
    __shared__ float act[EPB];

    const int t  = threadIdx.x;
    const int e0 = blockIdx.x * EPB;

    if (t < EPB) sidx[t] = ei[e0 + t];
    else         didx[t - EPB] = ei[EROW + e0 + (t - EPB)];
    gl[t] = gum[(size_t)e0 * 2 + t];
    __syncthreads();

    const int j   = t & 15;
    const int grp = t >> 4;
    const float4 w0 = ld4(&W2[j * 4]);
    const float4 w1 = ld4(&W2[64 + j * 4]);
    const float4 dk = make_float4(w0.x - w1.x, w0.y - w1.y,
                                  w0.z - w1.z, w0.w - w1.w);
    const float4 dw = make_float4(fabsf(dk.x), fabsf(dk.y),
                                  fabsf(dk.z), fabsf(dk.w));
    const float b20 = b2[0], b21 = b2[1];
    const float dB  = b20 - b21;

    union U8 { uint2 u; half4 h; };
    U8 ua[8], ub[8];
#pragma unroll
    for (int it = 0; it < 8; ++it) {
        const int el = grp * 8 + it;
        ua[it].u = *(const uint2*)&pH[(size_t)sidx[el] * 128 + j * 4];
        ub[it].u = *(const uint2*)&pH[(size_t)didx[el] * 128 + 64 + j * 4];
    }

#pragma unroll
    for (int it = 0; it < 8; ++it) {
        const int el = grp * 8 + it;
        const float a0 = (float)ua[it].h[0], a1 = (float)ua[it].h[1];
        const float a2 = (float)ua[it].h[2], a3 = (float)ua[it].h[3];
        const float c0 = (float)ub[it].h[0], c1 = (float)ub[it].h[1];
        const float c2 = (float)ub[it].h[2], c3 = (float)ub[it].h[3];
        const float r0 = fmaxf(a0 + c0, 0.f);
        const float r1 = fmaxf(a1 + c1, 0.f);
        const float r2 = fmaxf(a2 + c2, 0.f);
        const float r3 = fmaxf(a3 + c3, 0.f);
        float sc = r0 * dk.x + r1 * dk.y + r2 * dk.z + r3 * dk.w;
        float eb = dw.x * (fabsf(a0) + fabsf(c0)) + dw.y * (fabsf(a1) + fabsf(c1))
                 + dw.z * (fabsf(a2) + fabsf(c2)) + dw.w * (fabsf(a3) + fabsf(c3));
#pragma unroll
        for (int off = 1; off < 16; off <<= 1) {
            sc += __shfl_xor(sc, off, 16);
            eb += __shfl_xor(eb, off, 16);
        }
        const float g0 = gl[el * 2], g1 = gl[el * 2 + 1];
        const float gap = sc + dB + (g0 - g1);
        const float bound = eb * 0.0009765625f + 2e-5f;   // 2^-10 * eb + slack
        float av;
        if (fabsf(gap) > bound) {
            av = (gap >= 0.f) ? 1.f : 0.f;
        } else {
            // Exact fp32 recompute (rare; uniform within the 16-lane group).
            const float4 pa = ld4(&p[(size_t)sidx[el] * 128 + j * 4]);
            const float4 pb = ld4(&p[(size_t)didx[el] * 128 + 64 + j * 4]);
            const float q0 = fmaxf(pa.x + pb.x, 0.f);
            const float q1 = fmaxf(pa.y + pb.y, 0.f);
            const float q2 = fmaxf(pa.z + pb.z, 0.f);
            const float q3 = fmaxf(pa.w + pb.w, 0.f);
            float t0 = q0 * w0.x + q1 * w0.y + q2 * w0.z + q3 * w0.w;
            float t1 = q0 * w1.x + q1 * w1.y + q2 * w1.z + q3 * w1.w;
#pragma unroll
            for (int off = 1; off < 16; off <<= 1) {
                t0 += __shfl_xor(t0, off, 16);
                t1 += __shfl_xor(t1, off, 16);
            }
            const float ge = (t0 + b20 + g0) - (t1 + b21 + g1);
            av = (ge >= 0.f) ? 1.f : 0.f;
        }
        if (j == 0) act[el] = av;
    }
    __syncthreads();

    if (t < EPB) {
        const float a = act[t];
        const size_t e = (size_t)e0 + t;
        out[e]                  = a;
        out[EE + e]             = 1.f - a;
        out[2 * (size_t)EE + e] = 1.f - a;
    }
}

// ---------------------------------------------------------------------------
extern "C" void kernel_launch(void* const* d_in, const int* in_sizes, int n_in,
                              void* d_out, int out_size, void* d_ws, size_t ws_size,
                              hipStream_t stream)
{
    const float* trace  = (const float*)d_in[0];   // (2,100000,128)
    const float* W_lin  = (const float*)d_in[1];   // (256,256)
    const float* W_lin2 = (const float*)d_in[2];   // (128,256)
    const float* W_fc1  = (const float*)d_in[3];   // (64,256)
    const float* b_fc1  = (const float*)d_in[4];   // (64,)
    const float* W_fc2  = (const float*)d_in[5];   // (2,64)
    const float* b_fc2  = (const float*)d_in[6];   // (2,)
    const float* gum    = (const float*)d_in[7];   // (1600000,2)
    const int*   ei     = (const int*)  d_in[8];   // (2,4800000)
    float*       out    = (float*)d_out;           // (4800000,)

    // Workspace: h split-plane [NN x 256 dw] at 0 (102.4 MB); mvc split-plane
    // [NN x 128 dw] (51.2 MB); weight planes (459 KB). p (fp32, 51.2 MB) and
    // pH (fp16, 25.6 MB) overlay h's region (h dead after GEMM2). ~154 MB.
    char* ws = (char*)d_ws;
    unsigned*       hpl = (unsigned*)ws;
    unsigned*       mpl = (unsigned*)(ws + (size_t)NN * 256 * 4);
    unsigned*       W1i = (unsigned*)(ws + (size_t)NN * 256 * 4 + (size_t)NN * 128 * 4);
    unsigned*       W2i = W1i + 65536;
    unsigned*       W3i = W2i + 32768;
    float*          p   = (float*)ws;                                  // 51.2 MB
    unsigned short* pH  = (unsigned short*)(ws + (size_t)NN * 128 * 4); // +25.6 MB

    // Split weights into fp16 hi/lo interleaved planes.
    prep_w<<<448, 256, 0, stream>>>(W_lin, W_lin2, W_fc1, W1i, W2i, W3i);

    const int mB = (NN + 127) / 128;   // 782

    // h = relu(x @ W_lin^T), stored split
    gemm_mfma<0, 0><<<dim3(mB, 2), 256, 0, stream>>>(trace, W1i, nullptr, hpl, nullptr, nullptr, NN, 256, 256);
    // mvc = normalize_rows(h @ W_lin2^T), stored split
    gemm_mfma<1, 1><<<dim3(mB, 1), 256, 0, stream>>>(hpl, W2i, nullptr, mpl, nullptr, nullptr, NN, 256, 128);
    // p[n] = [W_fc1_left @ mvcn + b_fc1 | W_fc1_right @ mvcn], fp32 + fp16
    gemm_mfma<1, 2><<<dim3(mB, 1), 256, 0, stream>>>(mpl, W3i, b_fc1, nullptr, p, pH, NN, 128, 128);
    // per-edge score + hard mask (fp16 fast path, certified fp32 fallback)
    edge_k<<<EE / EPB, 256, 0, stream>>>(pH, p, ei, gum, W_fc2, b_fc2, out);
}

// Round 4
// 434.707 us; speedup vs baseline: 1.0283x; 1.0283x over previous
//
#include <hip/hip_runtime.h>

// Problem constants (fixed by the reference's setup_inputs)
#define NN   100000      // nodes
#define EE   1600000     // num_edge
#define EROW 4800000     // edge_index row length (3*NUM_EDGE)

typedef _Float16 half8 __attribute__((ext_vector_type(8)));
typedef _Float16 half4 __attribute__((ext_vector_type(4)));
typedef float    f32x4 __attribute__((ext_vector_type(4)));

__device__ __forceinline__ float4 ld4(const float* p){ return *(const float4*)p; }

// Split fp32 -> (hi fp16) + (lo fp16, scaled by 2048). Packed lo16=hi, hi16=lo.
__device__ __forceinline__ unsigned splitf(float v) {
    _Float16 h = (_Float16)v;
    float r = v - (float)h;
    _Float16 l = (_Float16)(r * 2048.0f);
    union { _Float16 f; unsigned short u; } uh, ul;
    uh.f = h; ul.f = l;
    return (unsigned)uh.u | ((unsigned)ul.u << 16);
}

// ---------------------------------------------------------------------------
// Weight prep: split W_lin (256x256), W_lin2 (128x256), repacked W_fc1
// (128x128: row j = W_fc1[j&63][(j>>6)*128 ..]) into interleaved half2 planes.
// ---------------------------------------------------------------------------
__global__ __launch_bounds__(256)
void prep_w(const float* __restrict__ W1, const float* __restrict__ W2,
            const float* __restrict__ W3, unsigned* __restrict__ o1,
            unsigned* __restrict__ o2, unsigned* __restrict__ o3)
{
    int idx = blockIdx.x * 256 + threadIdx.x;   // 448 blocks = 114688 threads
    if (idx < 65536) {
        o1[idx] = splitf(W1[idx]);
    } else if (idx < 98304) {
        int i = idx - 65536;
        o2[i] = splitf(W2[i]);
    } else {
        int i = idx - 98304;
        int j = i >> 7, k = i & 127;
        o3[i] = splitf(W3[(j & 63) * 256 + (j >> 6) * 128 + k]);
    }
}

// ---------------------------------------------------------------------------
// MFMA split-fp16 GEMM: C[M x No] = A[M x K] @ B[No x K]^T (+epilogue).
// 256 thr = 4 waves, wave grid 2x2, wave tile 64x64 (4x4 of 16x16x32 f16).
// 3 MFMA passes: acc_hi += Ah*Bh; acc_mid += Ah*Bl + Al*Bh; C = hi + mid/2048.
//
// R4 structure: NO LDS TILES, NO K-LOOP BARRIERS. R2 counters showed B is
// L2-resident and the trace fits in L3 (FETCH=102.5MB despite grid-y=2), so
// LDS only served 2x within-block frag dedup — cache-tier traffic, not HBM.
// R2/R3 showed depth-1 reg staging can't cover ~500-900cyc load latency
// (stall-bound: Mfma 15% + VALU 26%) and depth-2 reg staging spills
// (R3: WRITE_SIZE 100->279MB). So each wave now loads fragments DIRECTLY
// from global (A: 2x dwordx4 + split repack; B: 2x dwordx4 + deinterleave),
// K templated + fully unrolled: the compiler hoists loads across iterations
// with no barrier ever forcing a vmcnt drain; waves slip independently.
// Frag build reuses the R2-verified repack bitops verbatim.
//
// SRCA 0: A = trace fp32 (2-plane, split on the fly). 1: interleaved plane.
// EPI  0: relu, store split plane. 1: row-L2-normalize, store split plane.
//      2: += b_fc1 on cols 0-63, store fp32 + fp16 copies.
// ---------------------------------------------------------------------------
template<int SRCA, int EPI, int K>
__global__ __launch_bounds__(256, 2)
void gemm_mfma(const void* __restrict__ Asrc, const unsigned* __restrict__ Bw,
               const float* __restrict__ bias, unsigned* __restrict__ outS,
               float* __restrict__ outF, unsigned short* __restrict__ outH,
               int M, int No)
{
    __shared__ float sqv[128][2];      // EPI==1 cross-wave row-ssq scratch

    const int t     = threadIdx.x;
    const int wm    = (t >> 6) >> 1;   // wave m index (0..1)
    const int wn    = (t >> 6) & 1;    // wave n index (0..1)
    const int lane  = t & 63;
    const int lm    = lane & 15;
    const int q     = lane >> 4;
    const int mBase = blockIdx.x * 128;
    const int nBase = blockIdx.y * 128;

    f32x4 aH[4][4], aM[4][4];
#pragma unroll
    for (int i = 0; i < 4; ++i)
#pragma unroll
        for (int j = 0; j < 4; ++j) {
            aH[i][j] = (f32x4){0.f, 0.f, 0.f, 0.f};
            aM[i][j] = (f32x4){0.f, 0.f, 0.f, 0.f};
        }

    // Fragment row indices (A rows clamped to M-1; clamped rows never stored).
    int arow[4], brow[4];
#pragma unroll
    for (int i = 0; i < 4; ++i) {
        int r = mBase + wm * 64 + i * 16 + lm;
        arow[i] = r < M ? r : M - 1;
        brow[i] = nBase + wn * 64 + i * 16 + lm;
    }

    union HL { uint4 u; half8 h; };

#pragma unroll
    for (int kt = 0; kt < K / 32; ++kt) {
        const int k0 = kt * 32 + q * 8;   // this lane's 8-elem k-run

        half8 fAh[4], fAl[4], fBh[4], fBl[4];

        // ---- A fragments (direct global) ----
#pragma unroll
        for (int i = 0; i < 4; ++i) {
            HL H, L;
            if (SRCA == 0) {
                const float* ap = (const float*)Asrc
                    + (size_t)(k0 >> 7) * ((size_t)NN * 128)
                    + (size_t)arow[i] * 128 + (k0 & 127);
                float4 f0 = ld4(ap);
                float4 f1 = ld4(ap + 4);
                unsigned p0 = splitf(f0.x), p1 = splitf(f0.y);
                unsigned p2 = splitf(f0.z), p3 = splitf(f0.w);
                unsigned p4 = splitf(f1.x), p5 = splitf(f1.y);
                unsigned p6 = splitf(f1.z), p7 = splitf(f1.w);
                H.u.x = (p0 & 0xffffu) | (p1 << 16);
                H.u.y = (p2 & 0xffffu) | (p3 << 16);
                H.u.z = (p4 & 0xffffu) | (p5 << 16);
                H.u.w = (p6 & 0xffffu) | (p7 << 16);
                L.u.x = (p0 >> 16) | (p1 & 0xffff0000u);
                L.u.y = (p2 >> 16) | (p3 & 0xffff0000u);
                L.u.z = (p4 >> 16) | (p5 & 0xffff0000u);
                L.u.w = (p6 >> 16) | (p7 & 0xffff0000u);
            } else {
                const unsigned* ap = (const unsigned*)Asrc + (size_t)arow[i] * K + k0;
                uint4 u0 = *(const uint4*)ap;
                uint4 u1 = *(const uint4*)(ap + 4);
                H.u.x = (u0.x & 0xffffu) | (u0.y << 16);
                H.u.y = (u0.z & 0xffffu) | (u0.w << 16);
                H.u.z = (u1.x & 0xffffu) | (u1.y << 16);
                H.u.w = (u1.z & 0xffffu) | (u1.w << 16);
                L.u.x = (u0.x >> 16) | (u0.y & 0xffff0000u);
                L.u.y = (u0.z >> 16) | (u0.w & 0xffff0000u);
                L.u.z = (u1.x >> 16) | (u1.y & 0xffff0000u);
                L.u.w = (u1.z >> 16) | (u1.w & 0xffff0000u);
            }
            fAh[i] = H.h;
            fAl[i] = L.h;
        }

        // ---- B fragments (direct global; W-planes are L2-resident) ----
#pragma unroll
        for (int j = 0; j < 4; ++j) {
            const unsigned* bp = Bw + (size_t)brow[j] * K + k0;
            uint4 u0 = *(const uint4*)bp;
            uint4 u1 = *(const uint4*)(bp + 4);
            HL H, L;
            H.u.x = (u0.x & 0xffffu) | (u0.y << 16);
            H.u.y = (u0.z & 0xffffu) | (u0.w << 16);
            H.u.z = (u1.x & 0xffffu) | (u1.y << 16);
            H.u.w = (u1.z & 0xffffu) | (u1.w << 16);
            L.u.x = (u0.x >> 16) | (u0.y & 0xffff0000u);
            L.u.y = (u0.z >> 16) | (u0.w & 0xffff0000u);
            L.u.z = (u1.x >> 16) | (u1.y & 0xffff0000u);
            L.u.w = (u1.z >> 16) | (u1.w & 0xffff0000u);
            fBh[j] = H.h;
            fBl[j] = L.h;
        }

        // ---- MFMA: three passes, acc touched once per pass (no RAW stalls)
        __builtin_amdgcn_s_setprio(1);
#pragma unroll
        for (int i = 0; i < 4; ++i)
#pragma unroll
            for (int j = 0; j < 4; ++j)
                aH[i][j] = __builtin_amdgcn_mfma_f32_16x16x32_f16(fAh[i], fBh[j], aH[i][j], 0, 0, 0);
#pragma unroll
        for (int i = 0; i < 4; ++i)
#pragma unroll
            for (int j = 0; j < 4; ++j)
                aM[i][j] = __builtin_amdgcn_mfma_f32_16x16x32_f16(fAh[i], fBl[j], aM[i][j], 0, 0, 0);
#pragma unroll
        for (int i = 0; i < 4; ++i)
#pragma unroll
            for (int j = 0; j < 4; ++j)
                aM[i][j] = __builtin_amdgcn_mfma_f32_16x16x32_f16(fAl[i], fBh[j], aM[i][j], 0, 0, 0);
        __builtin_amdgcn_s_setprio(0);
    }

    // Combine split accumulators: C = hi + mid/2048
    const float cM = 1.0f / 2048.0f;
#pragma unroll
    for (int i = 0; i < 4; ++i)
#pragma unroll
        for (int j = 0; j < 4; ++j)
            aH[i][j] = aH[i][j] + aM[i][j] * cM;

    float nm[4][4];
    if (EPI == 1) {
#pragma unroll
        for (int i = 0; i < 4; ++i)
#pragma unroll
            for (int r = 0; r < 4; ++r) {
                float s = 0.f;
#pragma unroll
                for (int j = 0; j < 4; ++j) { float x = aH[i][j][r]; s = fmaf(x, x, s); }
#pragma unroll
                for (int off = 1; off < 16; off <<= 1) s += __shfl_xor(s, off, 16);
                if (lm == 0) sqv[wm * 64 + i * 16 + q * 4 + r][wn] = s;
            }
        __syncthreads();
#pragma unroll
        for (int i = 0; i < 4; ++i)
#pragma unroll
            for (int r = 0; r < 4; ++r) {
                const int rl = wm * 64 + i * 16 + q * 4 + r;
                nm[i][r] = fmaxf(sqrtf(sqv[rl][0] + sqv[rl][1]), 1e-12f);
            }
    }

    float bj[4] = {0.f, 0.f, 0.f, 0.f};
    if (EPI == 2 && wn == 0) {
#pragma unroll
        for (int j = 0; j < 4; ++j) bj[j] = bias[j * 16 + lm];
    }

#pragma unroll
    for (int i = 0; i < 4; ++i)
#pragma unroll
        for (int r = 0; r < 4; ++r) {
            const int m = mBase + wm * 64 + i * 16 + q * 4 + r;
            if (m < M) {
#pragma unroll
                for (int j = 0; j < 4; ++j) {
                    const int c = nBase + wn * 64 + j * 16 + lm;
                    float v = aH[i][j][r];
                    if (EPI == 0) { v = fmaxf(v, 0.f); outS[(size_t)m * No + c] = splitf(v); }
                    if (EPI == 1) { v = v / nm[i][r];  outS[(size_t)m * No + c] = splitf(v); }
                    if (EPI == 2) {
                        v += bj[j];
                        outF[(size_t)m * No + c] = v;
                        union { _Float16 f; unsigned short u; } cv; cv.f = (_Float16)v;
                        outH[(size_t)m * No + c] = cv.u;
                    }
                }
            }
        }
}

// ---------------------------------------------------------------------------
// Edge kernel: 128 edges/block, 16 lanes/edge, 8 edges/lane-group.
// Fast path gathers the fp16 p-table (8 B/lane per edge-half). The decision
// only needs the SIGN of the score gap: gap = sum relu(a+c)*(w0-w1) + dB + dg,
// so we accumulate ONE dot with dk = w0-w1 and butterfly-reduce 2 values
// (sc, eb). Certified bound: |fast gap - exact gap| <=
// 2^-10 * sum |dk|*(|a|+|c|) + 2e-5 slack; if |gap| <= bound, re-gather fp32
// and recompute exactly (path unchanged — it is the arbiter). Butterfly
// results are bit-identical across lanes -> branch uniform per 16-lane group.
// ---------------------------------------------------------------------------
#define EPB 128
__global__ __launch_bounds__(256, 4)
void edge_k(const unsigned short* __restrict__ pH, const float* __restrict__ p,
            const int* __restrict__ ei, const float* __restrict__ gum,
            const float* __restrict__ W2, const float* __restrict__ b2,
            float* __restrict__ out)
{
    __shared__ int   sidx[EPB];
    __shared__ int   didx[EPB];
    __shared__ float gl[2 * EPB];
    __shared__ float act[EPB];

    const int t  = threadIdx.x;
    const int e0 = blockIdx.x * EPB;

    if (t < EPB) sidx[t] = ei[e0 + t];
    else         didx[t - EPB] = ei[EROW + e0 + (t - EPB)];
    gl[t] = gum[(size_t)e0 * 2 + t];
    __syncthreads();

    const int j   = t & 15;
    const int grp = t >> 4;
    const float4 w0 = ld4(&W2[j * 4]);
    const float4 w1 = ld4(&W2[64 + j * 4]);
    const float4 dk = make_float4(w0.x - w1.x, w0.y - w1.y,
                                  w0.z - w1.z, w0.w - w1.w);
    const float4 dw = make_float4(fabsf(dk.x), fabsf(dk.y),
                                  fabsf(dk.z), fabsf(dk.w));
    const float b20 = b2[0], b21 = b2[1];
    const float dB  = b20 - b21;

    union U8 { uint2 u; half4 h; };
    U8 ua[8], ub[8];
#pragma unroll
    for (int it = 0; it < 8; ++it) {
        const int el = grp * 8 + it;
        ua[it].u = *(const uint2*)&pH[(size_t)sidx[el] * 128 + j * 4];
        ub[it].u = *(const uint2*)&pH[(size_t)didx[el] * 128 + 64 + j * 4];
    }

#pragma unroll
    for (int it = 0; it < 8; ++it) {
        const int el = grp * 8 + it;
        const float a0 = (float)ua[it].h[0], a1 = (float)ua[it].h[1];
        const float a2 = (float)ua[it].h[2], a3 = (float)ua[it].h[3];
        const float c0 = (float)ub[it].h[0], c1 = (float)ub[it].h[1];
        const float c2 = (float)ub[it].h[2], c3 = (float)ub[it].h[3];
        const float r0 = fmaxf(a0 + c0, 0.f);
        const float r1 = fmaxf(a1 + c1, 0.f);
        const float r2 = fmaxf(a2 + c2, 0.f);
        const float r3 = fmaxf(a3 + c3, 0.f);
        float sc = r0 * dk.x + r1 * dk.y + r2 * dk.z + r3 * dk.w;
        float eb = dw.x * (fabsf(a0) + fabsf(c0)) + dw.y * (fabsf(a1) + fabsf(c1))
                 + dw.z * (fabsf(a2) + fabsf(c2)) + dw.w * (fabsf(a3) + fabsf(c3));
#pragma unroll
        for (int off = 1; off < 16; off <<= 1) {
            sc += __shfl_xor(sc, off, 16);
            eb += __shfl_xor(eb, off, 16);
        }
        const float g0 = gl[el * 2], g1 = gl[el * 2 + 1];
        const float gap = sc + dB + (g0 - g1);
        const float bound = eb * 0.0009765625f + 2e-5f;   // 2^-10 * eb + slack
        float av;
        if (fabsf(gap) > bound) {
            av = (gap >= 0.f) ? 1.f : 0.f;
        } else {
            // Exact fp32 recompute (rare; uniform within the 16-lane group).
            const float4 pa = ld4(&p[(size_t)sidx[el] * 128 + j * 4]);
            const float4 pb = ld4(&p[(size_t)didx[el] * 128 + 64 + j * 4]);
            const float q0 = fmaxf(pa.x + pb.x, 0.f);
            const float q1 = fmaxf(pa.y + pb.y, 0.f);
            const float q2 = fmaxf(pa.z + pb.z, 0.f);
            const float q3 = fmaxf(pa.w + pb.w, 0.f);
            float t0 = q0 * w0.x + q1 * w0.y + q2 * w0.z + q3 * w0.w;
            float t1 = q0 * w1.x + q1 * w1.y + q2 * w1.z + q3 * w1.w;
#pragma unroll
            for (int off = 1; off < 16; off <<= 1) {
                t0 += __shfl_xor(t0, off, 16);
                t1 += __shfl_xor(t1, off, 16);
            }
            const float ge = (t0 + b20 + g0) - (t1 + b21 + g1);
            av = (ge >= 0.f) ? 1.f : 0.f;
        }
        if (j == 0) act[el] = av;
    }
    __syncthreads();

    if (t < EPB) {
        const float a = act[t];
        const size_t e = (size_t)e0 + t;
        out[e]                  = a;
        out[EE + e]             = 1.f - a;
        out[2 * (size_t)EE + e] = 1.f - a;
    }
}

// ---------------------------------------------------------------------------
extern "C" void kernel_launch(void* const* d_in, const int* in_sizes, int n_in,
                              void* d_out, int out_size, void* d_ws, size_t ws_size,
                              hipStream_t stream)
{
    const float* trace  = (const float*)d_in[0];   // (2,100000,128)
    const float* W_lin  = (const float*)d_in[1];   // (256,256)
    const float* W_lin2 = (const float*)d_in[2];   // (128,256)
    const float* W_fc1  = (const float*)d_in[3];   // (64,256)
    const float* b_fc1  = (const float*)d_in[4];   // (64,)
    const float* W_fc2  = (const float*)d_in[5];   // (2,64)
    const float* b_fc2  = (const float*)d_in[6];   // (2,)
    const float* gum    = (const float*)d_in[7];   // (1600000,2)
    const int*   ei     = (const int*)  d_in[8];   // (2,4800000)
    float*       out    = (float*)d_out;           // (4800000,)

    // Workspace: h split-plane [NN x 256 dw] at 0 (102.4 MB); mvc split-plane
    // [NN x 128 dw] (51.2 MB); weight planes (459 KB). p (fp32, 51.2 MB) and
    // pH (fp16, 25.6 MB) overlay h's region (h dead after GEMM2). ~154 MB.
    char* ws = (char*)d_ws;
    unsigned*       hpl = (unsigned*)ws;
    unsigned*       mpl = (unsigned*)(ws + (size_t)NN * 256 * 4);
    unsigned*       W1i = (unsigned*)(ws + (size_t)NN * 256 * 4 + (size_t)NN * 128 * 4);
    unsigned*       W2i = W1i + 65536;
    unsigned*       W3i = W2i + 32768;
    float*          p   = (float*)ws;                                  // 51.2 MB
    unsigned short* pH  = (unsigned short*)(ws + (size_t)NN * 128 * 4); // +25.6 MB

    // Split weights into fp16 hi/lo interleaved planes.
    prep_w<<<448, 256, 0, stream>>>(W_lin, W_lin2, W_fc1, W1i, W2i, W3i);

    const int mB = (NN + 127) / 128;   // 782

    // h = relu(x @ W_lin^T), stored split
    gemm_mfma<0, 0, 256><<<dim3(mB, 2), 256, 0, stream>>>(trace, W1i, nullptr, hpl, nullptr, nullptr, NN, 256);
    // mvc = normalize_rows(h @ W_lin2^T), stored split
    gemm_mfma<1, 1, 256><<<dim3(mB, 1), 256, 0, stream>>>(hpl, W2i, nullptr, mpl, nullptr, nullptr, NN, 128);
    // p[n] = [W_fc1_left @ mvcn + b_fc1 | W_fc1_right @ mvcn], fp32 + fp16
    gemm_mfma<1, 2, 128><<<dim3(mB, 1), 256, 0, stream>>>(mpl, W3i, b_fc1, nullptr, p, pH, NN, 128);
    // per-edge score + hard mask (fp16 fast path, certified fp32 fallback)
    edge_k<<<EE / EPB, 256, 0, stream>>>(pH, p, ei, gum, W_fc2, b_fc2, out);
}

// Round 5
// 369.883 us; speedup vs baseline: 1.2085x; 1.1753x over previous
//
#include <hip/hip_runtime.h>

// Problem constants (fixed by the reference's setup_inputs)
#define NN   100000      // nodes
#define EE   1600000     // num_edge
#define EROW 4800000     // edge_index row length (3*NUM_EDGE)

typedef _Float16 half8 __attribute__((ext_vector_type(8)));
typedef _Float16 half4 __attribute__((ext_vector_type(4)));
typedef float    f32x4 __attribute__((ext_vector_type(4)));

__device__ __forceinline__ float4 ld4(const float* p){ return *(const float4*)p; }

// Split fp32 -> (hi fp16) + (lo fp16, scaled by 2048). Packed lo16=hi, hi16=lo.
__device__ __forceinline__ unsigned splitf(float v) {
    _Float16 h = (_Float16)v;
    float r = v - (float)h;
    _Float16 l = (_Float16)(r * 2048.0f);
    union { _Float16 f; unsigned short u; } uh, ul;
    uh.f = h; ul.f = l;
    return (unsigned)uh.u | ((unsigned)ul.u << 16);
}

// Async global->LDS DMA, 16 B per lane. LDS dest = wave-uniform base + lane*16.
// CK-style addrspace casts (truncation to 32-bit AS3 offset is valid: generic
// LDS pointers carry the offset in the low 32 bits).
__device__ __forceinline__ void dma16(const void* g, void* l) {
    __builtin_amdgcn_global_load_lds(
        (const __attribute__((address_space(1))) unsigned*)((size_t)g),
        (__attribute__((address_space(3))) unsigned*)((size_t)l),
        16, 0, 0);
}

// ---------------------------------------------------------------------------
// Weight prep: split W_lin (256x256), W_lin2 (128x256), repacked W_fc1
// (128x128: row j = W_fc1[j&63][(j>>6)*128 ..]) into interleaved half2 planes.
// ---------------------------------------------------------------------------
__global__ __launch_bounds__(256)
void prep_w(const float* __restrict__ W1, const float* __restrict__ W2,
            const float* __restrict__ W3, unsigned* __restrict__ o1,
            unsigned* __restrict__ o2, unsigned* __restrict__ o3)
{
    int idx = blockIdx.x * 256 + threadIdx.x;   // 448 blocks = 114688 threads
    if (idx < 65536) {
        o1[idx] = splitf(W1[idx]);
    } else if (idx < 98304) {
        int i = idx - 65536;
        o2[i] = splitf(W2[i]);
    } else {
        int i = idx - 98304;
        int j = i >> 7, k = i & 127;
        o3[i] = splitf(W3[(j & 63) * 256 + (j >> 6) * 128 + k]);
    }
}

// ---------------------------------------------------------------------------
// MFMA split-fp16 GEMM: C[M x No] = A[M x K] @ B[No x K]^T (+epilogue).
// 256 thr = 4 waves, wave grid 2x2, wave tile 64x64 (4x4 of 16x16x32 f16).
// 3 MFMA passes: acc_hi += Ah*Bh; acc_mid += Ah*Bl + Al*Bh; C = hi + mid/2048.
//
// R5 structure (m97 ladder port): global_load_lds DMA staging of RAW tiles
// (A: fp32 or interleaved dwords; B: interleaved dwords), double-buffered
// 2x16KB each (64 KB LDS total), ONE __syncthreads per K-step (its implicit
// vmcnt(0) drains the NEXT tile's DMA — m97-style, ~full compute phase of
// latency cover, no staged VGPRs, no VGPR->LDS writes).
// Split/repack moved to the fragment-read side (VALU has 4x headroom; R2
// counters: VALUBusy 26%).
//
// LDS swizzle (both-sides involution, linear DMA dest): 16B chunk c of row r
// holds global chunk c ^ (r&7). DMA's linear lane slot (l&7) therefore
// pre-swizzles the GLOBAL source with col16 = (l&7) ^ (l>>3) (row&7 == l>>3
// for every chunk). Reads XOR the chunk index with (r&7): 64 lanes spread
// 8-per-16B-slot = the wave64 b128 throughput floor (vs 16-way unswizzled).
//
// SRCA 0: A = trace fp32 (2-plane, split on read). 1: interleaved plane.
// EPI  0: relu, store split plane. 1: row-L2-normalize, store split plane.
//      2: += b_fc1 on cols 0-63, store fp32 + fp16 copies.
// ---------------------------------------------------------------------------
template<int SRCA, int EPI, int K>
__global__ __launch_bounds__(256, 2)
void gemm_mfma(const void* __restrict__ Asrc, const unsigned* __restrict__ Bw,
               const float* __restrict__ bias, unsigned* __restrict__ outS,
               float* __restrict__ outF, unsigned short* __restrict__ outH,
               int M, int No)
{
    // Raw K-step tiles: 128 rows x 32 dwords (128 B/row), double-buffered.
    __shared__ __align__(16) unsigned bufA[2][128 * 32];
    __shared__ __align__(16) unsigned bufB[2][128 * 32];
    __shared__ float sqv[128][2];      // EPI==1 cross-wave row-ssq scratch

    const int t     = threadIdx.x;
    const int w     = t >> 6;          // wave id 0..3
    const int wm    = w >> 1;          // wave m index (0..1)
    const int wn    = w & 1;           // wave n index (0..1)
    const int lane  = t & 63;
    const int lm    = lane & 15;
    const int q     = lane >> 4;
    const int mBase = blockIdx.x * 128;
    const int nBase = blockIdx.y * 128;

    // DMA source swizzle: lane's linear LDS slot (l&7) gets global chunk
    // (l&7)^(l>>3); constant across the 4 chunk-instrs (row&7 == l>>3).
    const int col16 = (lane & 7) ^ (lane >> 3);

    f32x4 aH[4][4], aM[4][4];
#pragma unroll
    for (int i = 0; i < 4; ++i)
#pragma unroll
        for (int j = 0; j < 4; ++j) {
            aH[i][j] = (f32x4){0.f, 0.f, 0.f, 0.f};
            aM[i][j] = (f32x4){0.f, 0.f, 0.f, 0.f};
        }

    // Issue the DMA for K-tile kt into buf[sb]: 4 A-chunks + 4 B-chunks per
    // wave, 1 KB each (wave-uniform LDS base, per-lane global address).
    auto stage = [&](int sb, int kt) {
#pragma unroll
        for (int c = 0; c < 4; ++c) {
            const int row = w * 32 + c * 8 + (lane >> 3);   // local row 0..127
            unsigned* ldsA = &bufA[sb][w * 1024 + c * 256];
            unsigned* ldsB = &bufB[sb][w * 1024 + c * 256];
            int rgA = mBase + row; rgA = rgA < M ? rgA : M - 1;
            if (SRCA == 0) {
                const int kg    = kt * 32;
                const int plane = kg >> 7;
                const int ktl   = kg & 127;
                const float* gA = (const float*)Asrc
                    + (size_t)plane * ((size_t)NN * 128)
                    + (size_t)rgA * 128 + ktl + col16 * 4;
                dma16(gA, ldsA);
            } else {
                const unsigned* gA = (const unsigned*)Asrc
                    + (size_t)rgA * K + kt * 32 + col16 * 4;
                dma16(gA, ldsA);
            }
            const unsigned* gB = Bw + (size_t)(nBase + row) * K + kt * 32 + col16 * 4;
            dma16(gB, ldsB);
        }
    };

    union HL { uint4 u; half8 h; };

    constexpr int NK = K / 32;
    stage(0, 0);
    __syncthreads();   // drains vmcnt(0): tile 0 resident

#pragma unroll 2
    for (int kt = 0; kt < NK; ++kt) {
        const int b = kt & 1;
        if (kt + 1 < NK) stage(b ^ 1, kt + 1);   // in flight across compute

        half8 fAh[4], fAl[4], fBh[4], fBl[4];

        // ---- A fragments: swizzled raw read + split/deinterleave ----
#pragma unroll
        for (int i = 0; i < 4; ++i) {
            const int r = wm * 64 + i * 16 + lm;
            const int x = r & 7;
            const unsigned* p0p = &bufA[b][r * 32 + (((2 * q) ^ x) << 2)];
            const unsigned* p1p = &bufA[b][r * 32 + ((((2 * q) | 1) ^ x) << 2)];
            HL H, L;
            if (SRCA == 0) {
                float4 f0 = *(const float4*)p0p;
                float4 f1 = *(const float4*)p1p;
                unsigned p0 = splitf(f0.x), p1 = splitf(f0.y);
                unsigned p2 = splitf(f0.z), p3 = splitf(f0.w);
                unsigned p4 = splitf(f1.x), p5 = splitf(f1.y);
                unsigned p6 = splitf(f1.z), p7 = splitf(f1.w);
                H.u.x = (p0 & 0xffffu) | (p1 << 16);
                H.u.y = (p2 & 0xffffu) | (p3 << 16);
                H.u.z = (p4 & 0xffffu) | (p5 << 16);
                H.u.w = (p6 & 0xffffu) | (p7 << 16);
                L.u.x = (p0 >> 16) | (p1 & 0xffff0000u);
                L.u.y = (p2 >> 16) | (p3 & 0xffff0000u);
                L.u.z = (p4 >> 16) | (p5 & 0xffff0000u);
                L.u.w = (p6 >> 16) | (p7 & 0xffff0000u);
            } else {
                uint4 u0 = *(const uint4*)p0p;
                uint4 u1 = *(const uint4*)p1p;
                H.u.x = (u0.x & 0xffffu) | (u0.y << 16);
                H.u.y = (u0.z & 0xffffu) | (u0.w << 16);
                H.u.z = (u1.x & 0xffffu) | (u1.y << 16);
                H.u.w = (u1.z & 0xffffu) | (u1.w << 16);
                L.u.x = (u0.x >> 16) | (u0.y & 0xffff0000u);
                L.u.y = (u0.z >> 16) | (u0.w & 0xffff0000u);
                L.u.z = (u1.x >> 16) | (u1.y & 0xffff0000u);
                L.u.w = (u1.z >> 16) | (u1.w & 0xffff0000u);
            }
            fAh[i] = H.h;
            fAl[i] = L.h;
        }

        // ---- B fragments: swizzled raw read + deinterleave ----
#pragma unroll
        for (int j = 0; j < 4; ++j) {
            const int r = wn * 64 + j * 16 + lm;
            const int x = r & 7;
            uint4 u0 = *(const uint4*)&bufB[b][r * 32 + (((2 * q) ^ x) << 2)];
            uint4 u1 = *(const uint4*)&bufB[b][r * 32 + ((((2 * q) | 1) ^ x) << 2)];
            HL H, L;
            H.u.x = (u0.x & 0xffffu) | (u0.y << 16);
            H.u.y = (u0.z & 0xffffu) | (u0.w << 16);
            H.u.z = (u1.x & 0xffffu) | (u1.y << 16);
            H.u.w = (u1.z & 0xffffu) | (u1.w << 16);
            L.u.x = (u0.x >> 16) | (u0.y & 0xffff0000u);
            L.u.y = (u0.z >> 16) | (u0.w & 0xffff0000u);
            L.u.z = (u1.x >> 16) | (u1.y & 0xffff0000u);
            L.u.w = (u1.z >> 16) | (u1.w & 0xffff0000u);
            fBh[j] = H.h;
            fBl[j] = L.h;
        }

        // ---- MFMA: three passes, acc touched once per pass ----
        __builtin_amdgcn_s_setprio(1);
#pragma unroll
        for (int i = 0; i < 4; ++i)
#pragma unroll
            for (int j = 0; j < 4; ++j)
                aH[i][j] = __builtin_amdgcn_mfma_f32_16x16x32_f16(fAh[i], fBh[j], aH[i][j], 0, 0, 0);
#pragma unroll
        for (int i = 0; i < 4; ++i)
#pragma unroll
            for (int j = 0; j < 4; ++j)
                aM[i][j] = __builtin_amdgcn_mfma_f32_16x16x32_f16(fAh[i], fBl[j], aM[i][j], 0, 0, 0);
#pragma unroll
        for (int i = 0; i < 4; ++i)
#pragma unroll
            for (int j = 0; j < 4; ++j)
                aM[i][j] = __builtin_amdgcn_mfma_f32_16x16x32_f16(fAl[i], fBh[j], aM[i][j], 0, 0, 0);
        __builtin_amdgcn_s_setprio(0);

        // Implicit vmcnt(0)+lgkmcnt(0) drain + barrier: next tile resident,
        // and buf[b] reads complete -> safe to overwrite next iteration.
        if (kt + 1 < NK) __syncthreads();
    }

    // Combine split accumulators: C = hi + mid/2048
    const float cM = 1.0f / 2048.0f;
#pragma unroll
    for (int i = 0; i < 4; ++i)
#pragma unroll
        for (int j = 0; j < 4; ++j)
            aH[i][j] = aH[i][j] + aM[i][j] * cM;

    float nm[4][4];
    if (EPI == 1) {
#pragma unroll
        for (int i = 0; i < 4; ++i)
#pragma unroll
            for (int r = 0; r < 4; ++r) {
                float s = 0.f;
#pragma unroll
                for (int j = 0; j < 4; ++j) { float x = aH[i][j][r]; s = fmaf(x, x, s); }
#pragma unroll
                for (int off = 1; off < 16; off <<= 1) s += __shfl_xor(s, off, 16);
                if (lm == 0) sqv[wm * 64 + i * 16 + q * 4 + r][wn] = s;
            }
        __syncthreads();
#pragma unroll
        for (int i = 0; i < 4; ++i)
#pragma unroll
            for (int r = 0; r < 4; ++r) {
                const int rl = wm * 64 + i * 16 + q * 4 + r;
                nm[i][r] = fmaxf(sqrtf(sqv[rl][0] + sqv[rl][1]), 1e-12f);
            }
    }

    float bj[4] = {0.f, 0.f, 0.f, 0.f};
    if (EPI == 2 && wn == 0) {
#pragma unroll
        for (int j = 0; j < 4; ++j) bj[j] = bias[j * 16 + lm];
    }

#pragma unroll
    for (int i = 0; i < 4; ++i)
#pragma unroll
        for (int r = 0; r < 4; ++r) {
            const int m = mBase + wm * 64 + i * 16 + q * 4 + r;
            if (m < M) {
#pragma unroll
                for (int j = 0; j < 4; ++j) {
                    const int c = nBase + wn * 64 + j * 16 + lm;
                    float v = aH[i][j][r];
                    if (EPI == 0) { v = fmaxf(v, 0.f); outS[(size_t)m * No + c] = splitf(v); }
                    if (EPI == 1) { v = v / nm[i][r];  outS[(size_t)m * No + c] = splitf(v); }
                    if (EPI == 2) {
                        v += bj[j];
                        outF[(size_t)m * No + c] = v;
                        union { _Float16 f; unsigned short u; } cv; cv.f = (_Float16)v;
                        outH[(size_t)m * No + c] = cv.u;
                    }
                }
            }
        }
}

// ---------------------------------------------------------------------------
// Edge kernel: 128 edges/block, 16 lanes/edge, 8 edges/lane-group.
// Fast path gathers the fp16 p-table (8 B/lane per edge-half). The decision
// only needs the SIGN of the score gap: gap = sum relu(a+c)*(w0-w1) + dB + dg,
// so we accumulate ONE dot with dk = w0-w1 and butterfly-reduce 2 values
// (sc, eb). Certified bound: |fast gap - exact gap| <=
// 2^-10 * sum |dk|*(|a|+|c|) + 2e-5 slack; if |gap| <= bound, re-gather fp32
// and recompute exactly (path unchanged — it is the arbiter). Butterfly
// results are bit-identical across lanes -> branch uniform per 16-lane group.
// ---------------------------------------------------------------------------
#define EPB 128
__global__ __launch_bounds__(256, 4)
void edge_k(const unsigned short* __restrict__ pH, const float* __restrict__ p,
            const int* __restrict__ ei, const float* __restrict__ gum,
            const float* __restrict__ W2, const float* __restrict__ b2,
            float* __restrict__ out)
{
    __shared__ int   sidx[EPB];
    __shared__ int   didx[EPB];
    __shared__ float gl[2 * EPB];
    __shared__ float act[EPB];

    const int t  = threadIdx.x;
    const int e0 = blockIdx.x * EPB;

    if (t < EPB) sidx[t] = ei[e0 + t];
    else         didx[t - EPB] = ei[EROW + e0 + (t - EPB)];
    gl[t] = gum[(size_t)e0 * 2 + t];
    __syncthreads();

    const int j   = t & 15;
    const int grp = t >> 4;
    const float4 w0 = ld4(&W2[j * 4]);
    const float4 w1 = ld4(&W2[64 + j * 4]);
    const float4 dk = make_float4(w0.x - w1.x, w0.y - w1.y,
                                  w0.z - w1.z, w0.w - w1.w);
    const float4 dw = make_float4(fabsf(dk.x), fabsf(dk.y),
                                  fabsf(dk.z), fabsf(dk.w));
    const float b20 = b2[0], b21 = b2[1];
    const float dB  = b20 - b21;

    union U8 { uint2 u; half4 h; };
    U8 ua[8], ub[8];
#pragma unroll
    for (int it = 0; it < 8; ++it) {
        const int el = grp * 8 + it;
        ua[it].u = *(const uint2*)&pH[(size_t)sidx[el] * 128 + j * 4];
        ub[it].u = *(const uint2*)&pH[(size_t)didx[el] * 128 + 64 + j * 4];
    }

#pragma unroll
    for (int it = 0; it < 8; ++it) {
        const int el = grp * 8 + it;
        const float a0 = (float)ua[it].h[0], a1 = (float)ua[it].h[1];
        const float a2 = (float)ua[it].h[2], a3 = (float)ua[it].h[3];
        const float c0 = (float)ub[it].h[0], c1 = (float)ub[it].h[1];
        const float c2 = (float)ub[it].h[2], c3 = (float)ub[it].h[3];
        const float r0 = fmaxf(a0 + c0, 0.f);
        const float r1 = fmaxf(a1 + c1, 0.f);
        const float r2 = fmaxf(a2 + c2, 0.f);
        const float r3 = fmaxf(a3 + c3, 0.f);
        float sc = r0 * dk.x + r1 * dk.y + r2 * dk.z + r3 * dk.w;
        float eb = dw.x * (fabsf(a0) + fabsf(c0)) + dw.y * (fabsf(a1) + fabsf(c1))
                 + dw.z * (fabsf(a2) + fabsf(c2)) + dw.w * (fabsf(a3) + fabsf(c3));
#pragma unroll
        for (int off = 1; off < 16; off <<= 1) {
            sc += __shfl_xor(sc, off, 16);
            eb += __shfl_xor(eb, off, 16);
        }
        const float g0 = gl[el * 2], g1 = gl[el * 2 + 1];
        const float gap = sc + dB + (g0 - g1);
        const float bound = eb * 0.0009765625f + 2e-5f;   // 2^-10 * eb + slack
        float av;
        if (fabsf(gap) > bound) {
            av = (gap >= 0.f) ? 1.f : 0.f;
        } else {
            // Exact fp32 recompute (rare; uniform within the 16-lane group).
            const float4 pa = ld4(&p[(size_t)sidx[el] * 128 + j * 4]);
            const float4 pb = ld4(&p[(size_t)didx[el] * 128 + 64 + j * 4]);
            const float q0 = fmaxf(pa.x + pb.x, 0.f);
            const float q1 = fmaxf(pa.y + pb.y, 0.f);
            const float q2 = fmaxf(pa.z + pb.z, 0.f);
            const float q3 = fmaxf(pa.w + pb.w, 0.f);
            float t0 = q0 * w0.x + q1 * w0.y + q2 * w0.z + q3 * w0.w;
            float t1 = q0 * w1.x + q1 * w1.y + q2 * w1.z + q3 * w1.w;
#pragma unroll
            for (int off = 1; off < 16; off <<= 1) {
                t0 += __shfl_xor(t0, off, 16);
                t1 += __shfl_xor(t1, off, 16);
            }
            const float ge = (t0 + b20 + g0) - (t1 + b21 + g1);
            av = (ge >= 0.f) ? 1.f : 0.f;
        }
        if (j == 0) act[el] = av;
    }
    __syncthreads();

    if (t < EPB) {
        const float a = act[t];
        const size_t e = (size_t)e0 + t;
        out[e]                  = a;
        out[EE + e]             = 1.f - a;
        out[2 * (size_t)EE + e] = 1.f - a;
    }
}

// ---------------------------------------------------------------------------
extern "C" void kernel_launch(void* const* d_in, const int* in_sizes, int n_in,
                              void* d_out, int out_size, void* d_ws, size_t ws_size,
                              hipStream_t stream)
{
    const float* trace  = (const float*)d_in[0];   // (2,100000,128)
    const float* W_lin  = (const float*)d_in[1];   // (256,256)
    const float* W_lin2 = (const float*)d_in[2];   // (128,256)
    const float* W_fc1  = (const float*)d_in[3];   // (64,256)
    const float* b_fc1  = (const float*)d_in[4];   // (64,)
    const float* W_fc2  = (const float*)d_in[5];   // (2,64)
    const float* b_fc2  = (const float*)d_in[6];   // (2,)
    const float* gum    = (const float*)d_in[7];   // (1600000,2)
    const int*   ei     = (const int*)  d_in[8];   // (2,4800000)
    float*       out    = (float*)d_out;           // (4800000,)

    // Workspace: h split-plane [NN x 256 dw] at 0 (102.4 MB); mvc split-plane
    // [NN x 128 dw] (51.2 MB); weight planes (459 KB). p (fp32, 51.2 MB) and
    // pH (fp16, 25.6 MB) overlay h's region (h dead after GEMM2). ~154 MB.
    char* ws = (char*)d_ws;
    unsigned*       hpl = (unsigned*)ws;
    unsigned*       mpl = (unsigned*)(ws + (size_t)NN * 256 * 4);
    unsigned*       W1i = (unsigned*)(ws + (size_t)NN * 256 * 4 + (size_t)NN * 128 * 4);
    unsigned*       W2i = W1i + 65536;
    unsigned*       W3i = W2i + 32768;
    float*          p   = (float*)ws;                                  // 51.2 MB
    unsigned short* pH  = (unsigned short*)(ws + (size_t)NN * 128 * 4); // +25.6 MB

    // Split weights into fp16 hi/lo interleaved planes.
    prep_w<<<448, 256, 0, stream>>>(W_lin, W_lin2, W_fc1, W1i, W2i, W3i);

    const int mB = (NN + 127) / 128;   // 782

    // h = relu(x @ W_lin^T), stored split
    gemm_mfma<0, 0, 256><<<dim3(mB, 2), 256, 0, stream>>>(trace, W1i, nullptr, hpl, nullptr, nullptr, NN, 256);
    // mvc = normalize_rows(h @ W_lin2^T), stored split
    gemm_mfma<1, 1, 256><<<dim3(mB, 1), 256, 0, stream>>>(hpl, W2i, nullptr, mpl, nullptr, nullptr, NN, 128);
    // p[n] = [W_fc1_left @ mvcn + b_fc1 | W_fc1_right @ mvcn], fp32 + fp16
    gemm_mfma<1, 2, 128><<<dim3(mB, 1), 256, 0, stream>>>(mpl, W3i, b_fc1, nullptr, p, pH, NN, 128);
    // per-edge score + hard mask (fp16 fast path, certified fp32 fallback)
    edge_k<<<EE / EPB, 256, 0, stream>>>(pH, p, ei, gum, W_fc2, b_fc2, out);
}